// Round 11
// baseline (134.513 us; speedup 1.0000x reference)
//
#include <hip/hip_runtime.h>

#define NB 32
#define NS 2048
// softmax scale 1/sqrt(d_k)=0.5 folded with log2(e): s = log2(e)*score
#define QSCALE 0.72134752044448170367f

typedef float v2f __attribute__((ext_vector_type(2)));
typedef float v4f __attribute__((ext_vector_type(4)));

__device__ __forceinline__ v2f pkfma(v2f a, v2f b, v2f c) {
  return __builtin_elementwise_fma(a, b, c);
}

// Degree-6 Chebyshev-economized polynomial for 2^s on s in [-2.886, 2.886]
// (from e^u on [-2,2]; abs err ~4.5e-4, exact at s=0). Evaluated as packed
// f32 -> both heads' exp in 6 v_pk_fma_f32, ZERO trans-pipe usage.
#define EXP_C6 1.7700e-04f
#define EXP_C5 1.5714e-03f
#define EXP_C4 9.4881e-03f
#define EXP_C3 5.4474e-02f
#define EXP_C2 2.40464e-01f
#define EXP_C1 6.94280e-01f
#define EXP_C0 1.00001f

__device__ __forceinline__ v2f pk_exp2_poly(v2f s) {
  const v2f c6 = {EXP_C6, EXP_C6}, c5 = {EXP_C5, EXP_C5};
  const v2f c4 = {EXP_C4, EXP_C4}, c3 = {EXP_C3, EXP_C3};
  const v2f c2 = {EXP_C2, EXP_C2}, c1 = {EXP_C1, EXP_C1};
  const v2f c0 = {EXP_C0, EXP_C0};
  v2f r = pkfma(s, c6, c5);
  r = pkfma(r, s, c4);
  r = pkfma(r, s, c3);
  r = pkfma(r, s, c2);
  r = pkfma(r, s, c1);
  r = pkfma(r, s, c0);
  return r;
}

// ---------------------------------------------------------------------------
// Fully-fused attention: BLOCK-LOCAL split-K, no workspace, no 2nd kernel.
//   - block = 256 threads = 4 waves; block owns 128 q-rows (QPT=2 per lane).
//   - wave w processes k-quarter w (512 of 2048 k-rows).
//   - k staged in 2 chunks of 1024 rows (32 KB LDS), head-interleaved
//     (k0,k4,k1,k5)(k2,k6,k3,k7); wave LDS reads are broadcasts.
//   - chunk 1 global loads prefetched into registers across chunk 0 compute.
//   - scores bounded [-2,2] -> exp replaced by packed poly (no v_exp_f32:
//     the trans pipe was the invariant-wall suspect across R5-R10).
//   - merge: waves 1-3 dump partials via LDS (stride 21), wave 0 finalizes.
// ---------------------------------------------------------------------------
__global__ __launch_bounds__(256, 2) void attn_fused_kernel(
    const float* __restrict__ x, const float* __restrict__ theta,
    const float* __restrict__ Wout, float* __restrict__ outp) {
  __shared__ __align__(16) float kv[1024 * 8];

  const int b = blockIdx.y;
  const int t = threadIdx.x;
  const int w = t >> 6;    // wave index == k-quarter
  const int lane = t & 63;
  const int qbase = blockIdx.x * 128;

  float th[8];
#pragma unroll
  for (int e = 0; e < 8; ++e) th[e] = theta[e];

  // ---- stage chunk 0 (1024 rows; 256 per quarter) ----
#pragma unroll
  for (int i = 0; i < 4; ++i) {
    const int l = t + 256 * i;
    const int qtr = l >> 8;
    const int rr = l & 255;
    const int gk = qtr * 512 + rr;  // chunk 0
    const float4* xr = (const float4*)(x + ((size_t)b * NS + gk) * 8);
    float4 lo = xr[0], hi = xr[1];
    lo.x = __cosf(lo.x + th[0]);
    lo.y = __cosf(lo.y + th[1]);
    lo.z = __cosf(lo.z + th[2]);
    lo.w = __cosf(lo.w + th[3]);
    hi.x = __cosf(hi.x + th[4]);
    hi.y = __cosf(hi.y + th[5]);
    hi.z = __cosf(hi.z + th[6]);
    hi.w = __cosf(hi.w + th[7]);
    ((float4*)kv)[2 * l] = make_float4(lo.x, hi.x, lo.y, hi.y);
    ((float4*)kv)[2 * l + 1] = make_float4(lo.z, hi.z, lo.w, hi.w);
  }

  // ---- prefetch chunk 1's raw x rows into registers ----
  float4 pf[4][2];
#pragma unroll
  for (int i = 0; i < 4; ++i) {
    const int l = t + 256 * i;
    const int qtr = l >> 8;
    const int rr = l & 255;
    const int gk = qtr * 512 + 256 + rr;  // chunk 1
    const float4* xr = (const float4*)(x + ((size_t)b * NS + gk) * 8);
    pf[i][0] = xr[0];
    pf[i][1] = xr[1];
  }

  // This lane's 2 query rows as head-interleaved pairs, pre-scaled.
  v2f qp[2][4];
#pragma unroll
  for (int g = 0; g < 2; ++g) {
    const float4* xq =
        (const float4*)(x + ((size_t)b * NS + qbase + 64 * g + lane) * 8);
    float4 lo = xq[0], hi = xq[1];
    qp[g][0] = (v2f){__cosf(lo.x + th[0]) * QSCALE, __cosf(hi.x + th[4]) * QSCALE};
    qp[g][1] = (v2f){__cosf(lo.y + th[1]) * QSCALE, __cosf(hi.y + th[5]) * QSCALE};
    qp[g][2] = (v2f){__cosf(lo.z + th[2]) * QSCALE, __cosf(hi.z + th[6]) * QSCALE};
    qp[g][3] = (v2f){__cosf(lo.w + th[3]) * QSCALE, __cosf(hi.w + th[7]) * QSCALE};
  }

  v2f acc[2][4];
  v2f den[2];
#pragma unroll
  for (int g = 0; g < 2; ++g) {
    acc[g][0] = (v2f){0.f, 0.f};
    acc[g][1] = (v2f){0.f, 0.f};
    acc[g][2] = (v2f){0.f, 0.f};
    acc[g][3] = (v2f){0.f, 0.f};
    den[g] = (v2f){0.f, 0.f};
  }

  __syncthreads();  // (1) chunk 0 staged

  // ---- compute chunk 0 ----
  {
    const v4f* kp = (const v4f*)kv + (size_t)w * 512;
#pragma unroll 4
    for (int j = 0; j < 256; ++j) {
      v4f A = kp[2 * j];
      v4f Bv = kp[2 * j + 1];
      v2f kk0 = A.xy, kk1 = A.zw, kk2 = Bv.xy, kk3 = Bv.zw;
#pragma unroll
      for (int g = 0; g < 2; ++g) {
        v2f s = qp[g][0] * kk0;
        s = pkfma(qp[g][1], kk1, s);
        s = pkfma(qp[g][2], kk2, s);
        s = pkfma(qp[g][3], kk3, s);
        v2f P = pk_exp2_poly(s);
        acc[g][0] = pkfma(P, kk0, acc[g][0]);
        acc[g][1] = pkfma(P, kk1, acc[g][1]);
        acc[g][2] = pkfma(P, kk2, acc[g][2]);
        acc[g][3] = pkfma(P, kk3, acc[g][3]);
        den[g] = den[g] + P;
      }
    }
  }

  __syncthreads();  // (2) chunk 0 fully consumed

  // ---- restage chunk 1 from prefetched registers ----
#pragma unroll
  for (int i = 0; i < 4; ++i) {
    const int l = t + 256 * i;
    float4 lo = pf[i][0], hi = pf[i][1];
    lo.x = __cosf(lo.x + th[0]);
    lo.y = __cosf(lo.y + th[1]);
    lo.z = __cosf(lo.z + th[2]);
    lo.w = __cosf(lo.w + th[3]);
    hi.x = __cosf(hi.x + th[4]);
    hi.y = __cosf(hi.y + th[5]);
    hi.z = __cosf(hi.z + th[6]);
    hi.w = __cosf(hi.w + th[7]);
    ((float4*)kv)[2 * l] = make_float4(lo.x, hi.x, lo.y, hi.y);
    ((float4*)kv)[2 * l + 1] = make_float4(lo.z, hi.z, lo.w, hi.w);
  }

  __syncthreads();  // (3) chunk 1 staged

  // ---- compute chunk 1 ----
  {
    const v4f* kp = (const v4f*)kv + (size_t)w * 512;
#pragma unroll 4
    for (int j = 0; j < 256; ++j) {
      v4f A = kp[2 * j];
      v4f Bv = kp[2 * j + 1];
      v2f kk0 = A.xy, kk1 = A.zw, kk2 = Bv.xy, kk3 = Bv.zw;
#pragma unroll
      for (int g = 0; g < 2; ++g) {
        v2f s = qp[g][0] * kk0;
        s = pkfma(qp[g][1], kk1, s);
        s = pkfma(qp[g][2], kk2, s);
        s = pkfma(qp[g][3], kk3, s);
        v2f P = pk_exp2_poly(s);
        acc[g][0] = pkfma(P, kk0, acc[g][0]);
        acc[g][1] = pkfma(P, kk1, acc[g][1]);
        acc[g][2] = pkfma(P, kk2, acc[g][2]);
        acc[g][3] = pkfma(P, kk3, acc[g][3]);
        den[g] = den[g] + P;
      }
    }
  }

  // ---- block-local split-K merge through LDS ----
  __syncthreads();  // (4)
  if (w > 0) {
    float* mb = kv + ((size_t)(w - 1) * 64 + lane) * 21;
#pragma unroll
    for (int g = 0; g < 2; ++g) {
      mb[10 * g + 0] = acc[g][0].x;
      mb[10 * g + 1] = acc[g][0].y;
      mb[10 * g + 2] = acc[g][1].x;
      mb[10 * g + 3] = acc[g][1].y;
      mb[10 * g + 4] = acc[g][2].x;
      mb[10 * g + 5] = acc[g][2].y;
      mb[10 * g + 6] = acc[g][3].x;
      mb[10 * g + 7] = acc[g][3].y;
      mb[10 * g + 8] = den[g].x;
      mb[10 * g + 9] = den[g].y;
    }
  }
  __syncthreads();  // (5)
  if (w == 0) {
#pragma unroll
    for (int m = 0; m < 3; ++m) {
      const float* mb = kv + ((size_t)m * 64 + lane) * 21;
#pragma unroll
      for (int g = 0; g < 2; ++g) {
        acc[g][0].x += mb[10 * g + 0];
        acc[g][0].y += mb[10 * g + 1];
        acc[g][1].x += mb[10 * g + 2];
        acc[g][1].y += mb[10 * g + 3];
        acc[g][2].x += mb[10 * g + 4];
        acc[g][2].y += mb[10 * g + 5];
        acc[g][3].x += mb[10 * g + 6];
        acc[g][3].y += mb[10 * g + 7];
        den[g].x += mb[10 * g + 8];
        den[g].y += mb[10 * g + 9];
      }
    }
#pragma unroll
    for (int g = 0; g < 2; ++g) {
      const int q = qbase + 64 * g + lane;
      const float i0 = 1.0f / den[g].x, i1 = 1.0f / den[g].y;
      float m8[8] = {acc[g][0].x * i0, acc[g][1].x * i0, acc[g][2].x * i0,
                     acc[g][3].x * i0, acc[g][0].y * i1, acc[g][1].y * i1,
                     acc[g][2].y * i1, acc[g][3].y * i1};
      float o[8];
#pragma unroll
      for (int e = 0; e < 8; ++e) {
        float s = 0.f;
#pragma unroll
        for (int f = 0; f < 8; ++f) s += m8[f] * Wout[e * 8 + f];
        o[e] = s;
      }
      float4* op = (float4*)(outp + ((size_t)b * NS + q) * 8);
      op[0] = make_float4(o[0], o[1], o[2], o[3]);
      op[1] = make_float4(o[4], o[5], o[6], o[7]);
    }
  }
}

extern "C" void kernel_launch(void* const* d_in, const int* in_sizes, int n_in,
                              void* d_out, int out_size, void* d_ws,
                              size_t ws_size, hipStream_t stream) {
  const float* x = (const float*)d_in[0];      // [32, 2048, 8]
  const float* theta = (const float*)d_in[1];  // [8]
  const float* W = (const float*)d_in[2];      // [8, 8]
  float* out = (float*)d_out;                  // [32, 2048, 8]
  (void)d_ws;
  (void)ws_size;

  // 512 blocks (16 q-chunks x 32 batches) = 2 blocks/CU, 8 waves/CU.
  attn_fused_kernel<<<dim3(NS / 128, NB), 256, 0, stream>>>(x, theta, W, out);
}

// Round 13
// 124.200 us; speedup vs baseline: 1.0830x; 1.0830x over previous
//
#include <hip/hip_runtime.h>

#define NB 32
#define NS 2048
// softmax scale 1/sqrt(d_k)=0.5 folded with log2(e): s = log2(e)*score
#define QSCALE 0.72134752044448170367f

typedef float v2f __attribute__((ext_vector_type(2)));
typedef float v4f __attribute__((ext_vector_type(4)));
typedef __fp16 h2 __attribute__((ext_vector_type(2)));
typedef __fp16 h4 __attribute__((ext_vector_type(4)));
typedef __fp16 h8 __attribute__((ext_vector_type(8)));

__device__ __forceinline__ v2f pkfma(v2f a, v2f b, v2f c) {
  return __builtin_elementwise_fma(a, b, c);  // v_pk_fma_f32
}

// ---------------------------------------------------------------------------
// Fully-fused attention: BLOCK-LOCAL split-K, no workspace, no 2nd kernel.
//   - block = 256 threads = 4 waves; block owns 128 q-rows (QPT=2 per lane).
//   - wave w processes k-quarter w (512 of 2048 k-rows).
//   - k staged in 2 chunks of 1024 rows, TWO LDS copies:
//       kvf: f32 head-interleaved (k0,k4,k1,k5)(k2,k6,k3,k7) for the packed
//            P*k accumulates (32 KB)
//       kvh: f16 natural order (k0..k7) = one b128/row for the QK dot via
//            v_dot2_f32_f16 (16 KB) -- fdot2 is full-rate (2cyc) vs pk (4cyc),
//            cutting the dot from 16 to 8 issue-cycles per eval.
//     (R11 established wall = 1.35 x VALU-issue-cycles, invariant; the only
//      lever is fewer issue cycles per eval: 52 -> 44.)
//   - chunk 1 global loads prefetched into registers across chunk 0 compute.
//   - scores bounded [-2,2] -> single-pass exp (v_exp_f32), no max needed.
//   - merge: waves 1-3 dump partials via LDS (stride 21), wave 0 finalizes.
// ---------------------------------------------------------------------------
__global__ __launch_bounds__(256, 2) void attn_fused_kernel(
    const float* __restrict__ x, const float* __restrict__ theta,
    const float* __restrict__ Wout, float* __restrict__ outp) {
  __shared__ __align__(16) float kvf[1024 * 8];  // f32 interleaved
  __shared__ __align__(16) h8 kvh[1024];         // f16 natural

  const int b = blockIdx.y;
  const int t = threadIdx.x;
  const int w = t >> 6;    // wave index == k-quarter
  const int lane = t & 63;
  const int qbase = blockIdx.x * 128;

  float th[8];
#pragma unroll
  for (int e = 0; e < 8; ++e) th[e] = theta[e];

  // ---- stage chunk 0 (1024 rows; 256 per quarter) ----
#pragma unroll
  for (int i = 0; i < 4; ++i) {
    const int l = t + 256 * i;
    const int qtr = l >> 8;
    const int rr = l & 255;
    const int gk = qtr * 512 + rr;  // chunk 0
    const float4* xr = (const float4*)(x + ((size_t)b * NS + gk) * 8);
    float4 lo = xr[0], hi = xr[1];
    lo.x = __cosf(lo.x + th[0]);
    lo.y = __cosf(lo.y + th[1]);
    lo.z = __cosf(lo.z + th[2]);
    lo.w = __cosf(lo.w + th[3]);
    hi.x = __cosf(hi.x + th[4]);
    hi.y = __cosf(hi.y + th[5]);
    hi.z = __cosf(hi.z + th[6]);
    hi.w = __cosf(hi.w + th[7]);
    ((float4*)kvf)[2 * l] = make_float4(lo.x, hi.x, lo.y, hi.y);
    ((float4*)kvf)[2 * l + 1] = make_float4(lo.z, hi.z, lo.w, hi.w);
    h2 a = __builtin_amdgcn_cvt_pkrtz(lo.x, lo.y);
    h2 bb = __builtin_amdgcn_cvt_pkrtz(lo.z, lo.w);
    h2 c = __builtin_amdgcn_cvt_pkrtz(hi.x, hi.y);
    h2 d = __builtin_amdgcn_cvt_pkrtz(hi.z, hi.w);
    h4 ab = __builtin_shufflevector(a, bb, 0, 1, 2, 3);
    h4 cd = __builtin_shufflevector(c, d, 0, 1, 2, 3);
    kvh[l] = __builtin_shufflevector(ab, cd, 0, 1, 2, 3, 4, 5, 6, 7);
  }

  // ---- prefetch chunk 1's raw x rows into registers ----
  float4 pf[4][2];
#pragma unroll
  for (int i = 0; i < 4; ++i) {
    const int l = t + 256 * i;
    const int qtr = l >> 8;
    const int rr = l & 255;
    const int gk = qtr * 512 + 256 + rr;  // chunk 1
    const float4* xr = (const float4*)(x + ((size_t)b * NS + gk) * 8);
    pf[i][0] = xr[0];
    pf[i][1] = xr[1];
  }

  // This lane's 2 query rows: f16 pairs (natural order, pre-scaled).
  h2 qh[2][4];
#pragma unroll
  for (int g = 0; g < 2; ++g) {
    const float4* xq =
        (const float4*)(x + ((size_t)b * NS + qbase + 64 * g + lane) * 8);
    float4 lo = xq[0], hi = xq[1];
    float q0 = __cosf(lo.x + th[0]) * QSCALE;
    float q1 = __cosf(lo.y + th[1]) * QSCALE;
    float q2 = __cosf(lo.z + th[2]) * QSCALE;
    float q3 = __cosf(lo.w + th[3]) * QSCALE;
    float q4 = __cosf(hi.x + th[4]) * QSCALE;
    float q5 = __cosf(hi.y + th[5]) * QSCALE;
    float q6 = __cosf(hi.z + th[6]) * QSCALE;
    float q7 = __cosf(hi.w + th[7]) * QSCALE;
    qh[g][0] = __builtin_amdgcn_cvt_pkrtz(q0, q1);
    qh[g][1] = __builtin_amdgcn_cvt_pkrtz(q2, q3);
    qh[g][2] = __builtin_amdgcn_cvt_pkrtz(q4, q5);
    qh[g][3] = __builtin_amdgcn_cvt_pkrtz(q6, q7);
  }

  v2f acc[2][4];  // acc[g][i] = (sum p0*k_i, sum p1*k_{4+i})
  v2f den[2];     // (sum p0, sum p1)
#pragma unroll
  for (int g = 0; g < 2; ++g) {
    acc[g][0] = (v2f){0.f, 0.f};
    acc[g][1] = (v2f){0.f, 0.f};
    acc[g][2] = (v2f){0.f, 0.f};
    acc[g][3] = (v2f){0.f, 0.f};
    den[g] = (v2f){0.f, 0.f};
  }

  __syncthreads();  // (1) chunk 0 staged

  // ---- compute chunk 0: wave w reads rows [w*256, w*256+256) ----
  {
    const v4f* kp = (const v4f*)kvf + (size_t)w * 512;
    const h8* kph = kvh + (size_t)w * 256;
#pragma unroll 4
    for (int j = 0; j < 256; ++j) {
      v4f A = kp[2 * j];
      v4f Bv = kp[2 * j + 1];
      v2f kk0 = A.xy, kk1 = A.zw, kk2 = Bv.xy, kk3 = Bv.zw;
      h8 K = kph[j];
      h2 kA = __builtin_shufflevector(K, K, 0, 1);
      h2 kB = __builtin_shufflevector(K, K, 2, 3);
      h2 kC = __builtin_shufflevector(K, K, 4, 5);
      h2 kD = __builtin_shufflevector(K, K, 6, 7);
#pragma unroll
      for (int g = 0; g < 2; ++g) {
        float s0 = __builtin_amdgcn_fdot2(
            qh[g][0], kA, __builtin_amdgcn_fdot2(qh[g][1], kB, 0.f, false),
            false);
        float s1 = __builtin_amdgcn_fdot2(
            qh[g][2], kC, __builtin_amdgcn_fdot2(qh[g][3], kD, 0.f, false),
            false);
        v2f P;
        P.x = __builtin_amdgcn_exp2f(s0);
        P.y = __builtin_amdgcn_exp2f(s1);
        acc[g][0] = pkfma(P, kk0, acc[g][0]);
        acc[g][1] = pkfma(P, kk1, acc[g][1]);
        acc[g][2] = pkfma(P, kk2, acc[g][2]);
        acc[g][3] = pkfma(P, kk3, acc[g][3]);
        den[g] = den[g] + P;
      }
    }
  }

  __syncthreads();  // (2) chunk 0 fully consumed

  // ---- restage chunk 1 from prefetched registers ----
#pragma unroll
  for (int i = 0; i < 4; ++i) {
    const int l = t + 256 * i;
    float4 lo = pf[i][0], hi = pf[i][1];
    lo.x = __cosf(lo.x + th[0]);
    lo.y = __cosf(lo.y + th[1]);
    lo.z = __cosf(lo.z + th[2]);
    lo.w = __cosf(lo.w + th[3]);
    hi.x = __cosf(hi.x + th[4]);
    hi.y = __cosf(hi.y + th[5]);
    hi.z = __cosf(hi.z + th[6]);
    hi.w = __cosf(hi.w + th[7]);
    ((float4*)kvf)[2 * l] = make_float4(lo.x, hi.x, lo.y, hi.y);
    ((float4*)kvf)[2 * l + 1] = make_float4(lo.z, hi.z, lo.w, hi.w);
    h2 a = __builtin_amdgcn_cvt_pkrtz(lo.x, lo.y);
    h2 bb = __builtin_amdgcn_cvt_pkrtz(lo.z, lo.w);
    h2 c = __builtin_amdgcn_cvt_pkrtz(hi.x, hi.y);
    h2 d = __builtin_amdgcn_cvt_pkrtz(hi.z, hi.w);
    h4 ab = __builtin_shufflevector(a, bb, 0, 1, 2, 3);
    h4 cd = __builtin_shufflevector(c, d, 0, 1, 2, 3);
    kvh[l] = __builtin_shufflevector(ab, cd, 0, 1, 2, 3, 4, 5, 6, 7);
  }

  __syncthreads();  // (3) chunk 1 staged

  // ---- compute chunk 1 ----
  {
    const v4f* kp = (const v4f*)kvf + (size_t)w * 512;
    const h8* kph = kvh + (size_t)w * 256;
#pragma unroll 4
    for (int j = 0; j < 256; ++j) {
      v4f A = kp[2 * j];
      v4f Bv = kp[2 * j + 1];
      v2f kk0 = A.xy, kk1 = A.zw, kk2 = Bv.xy, kk3 = Bv.zw;
      h8 K = kph[j];
      h2 kA = __builtin_shufflevector(K, K, 0, 1);
      h2 kB = __builtin_shufflevector(K, K, 2, 3);
      h2 kC = __builtin_shufflevector(K, K, 4, 5);
      h2 kD = __builtin_shufflevector(K, K, 6, 7);
#pragma unroll
      for (int g = 0; g < 2; ++g) {
        float s0 = __builtin_amdgcn_fdot2(
            qh[g][0], kA, __builtin_amdgcn_fdot2(qh[g][1], kB, 0.f, false),
            false);
        float s1 = __builtin_amdgcn_fdot2(
            qh[g][2], kC, __builtin_amdgcn_fdot2(qh[g][3], kD, 0.f, false),
            false);
        v2f P;
        P.x = __builtin_amdgcn_exp2f(s0);
        P.y = __builtin_amdgcn_exp2f(s1);
        acc[g][0] = pkfma(P, kk0, acc[g][0]);
        acc[g][1] = pkfma(P, kk1, acc[g][1]);
        acc[g][2] = pkfma(P, kk2, acc[g][2]);
        acc[g][3] = pkfma(P, kk3, acc[g][3]);
        den[g] = den[g] + P;
      }
    }
  }

  // ---- block-local split-K merge through LDS ----
  __syncthreads();  // (4)
  if (w > 0) {
    // stride 21 floats per lane: gcd(21,32)=1 -> no systematic bank conflict
    float* mb = kvf + ((size_t)(w - 1) * 64 + lane) * 21;
#pragma unroll
    for (int g = 0; g < 2; ++g) {
      mb[10 * g + 0] = acc[g][0].x;
      mb[10 * g + 1] = acc[g][0].y;
      mb[10 * g + 2] = acc[g][1].x;
      mb[10 * g + 3] = acc[g][1].y;
      mb[10 * g + 4] = acc[g][2].x;
      mb[10 * g + 5] = acc[g][2].y;
      mb[10 * g + 6] = acc[g][3].x;
      mb[10 * g + 7] = acc[g][3].y;
      mb[10 * g + 8] = den[g].x;
      mb[10 * g + 9] = den[g].y;
    }
  }
  __syncthreads();  // (5)
  if (w == 0) {
#pragma unroll
    for (int m = 0; m < 3; ++m) {
      const float* mb = kvf + ((size_t)m * 64 + lane) * 21;
#pragma unroll
      for (int g = 0; g < 2; ++g) {
        acc[g][0].x += mb[10 * g + 0];
        acc[g][0].y += mb[10 * g + 1];
        acc[g][1].x += mb[10 * g + 2];
        acc[g][1].y += mb[10 * g + 3];
        acc[g][2].x += mb[10 * g + 4];
        acc[g][2].y += mb[10 * g + 5];
        acc[g][3].x += mb[10 * g + 6];
        acc[g][3].y += mb[10 * g + 7];
        den[g].x += mb[10 * g + 8];
        den[g].y += mb[10 * g + 9];
      }
    }
    // normalize + project (out = m @ W_out^T) + store
#pragma unroll
    for (int g = 0; g < 2; ++g) {
      const int q = qbase + 64 * g + lane;
      const float i0 = 1.0f / den[g].x, i1 = 1.0f / den[g].y;
      float m8[8] = {acc[g][0].x * i0, acc[g][1].x * i0, acc[g][2].x * i0,
                     acc[g][3].x * i0, acc[g][0].y * i1, acc[g][1].y * i1,
                     acc[g][2].y * i1, acc[g][3].y * i1};
      float o[8];
#pragma unroll
      for (int e = 0; e < 8; ++e) {
        float s = 0.f;
#pragma unroll
        for (int f = 0; f < 8; ++f) s += m8[f] * Wout[e * 8 + f];
        o[e] = s;
      }
      float4* op = (float4*)(outp + ((size_t)b * NS + q) * 8);
      op[0] = make_float4(o[0], o[1], o[2], o[3]);
      op[1] = make_float4(o[4], o[5], o[6], o[7]);
    }
  }
}

extern "C" void kernel_launch(void* const* d_in, const int* in_sizes, int n_in,
                              void* d_out, int out_size, void* d_ws,
                              size_t ws_size, hipStream_t stream) {
  const float* x = (const float*)d_in[0];      // [32, 2048, 8]
  const float* theta = (const float*)d_in[1];  // [8]
  const float* W = (const float*)d_in[2];      // [8, 8]
  float* out = (float*)d_out;                  // [32, 2048, 8]
  (void)d_ws;
  (void)ws_size;

  // 512 blocks (16 q-chunks x 32 batches) = 2 blocks/CU (48 KB LDS each),
  // 8 waves/CU.
  attn_fused_kernel<<<dim3(NS / 128, NB), 256, 0, stream>>>(x, theta, W, out);
}

// Round 14
// 117.970 us; speedup vs baseline: 1.1402x; 1.0528x over previous
//
#include <hip/hip_runtime.h>

#define NB 32
#define NS 2048
// softmax scale 1/sqrt(d_k)=0.5 folded with log2(e) so we can use v_exp_f32 (2^x)
#define QSCALE 0.72134752044448170367f

typedef float v2f __attribute__((ext_vector_type(2)));
typedef float v4f __attribute__((ext_vector_type(4)));

// Packed f32 math via native vector ops -> LLVM selects v_pk_{mul,fma,add}_f32
// on gfx90a+ with correct op_sel/op_sel_hi.
__device__ __forceinline__ v2f pkfma(v2f a, v2f b, v2f c) {
  return __builtin_elementwise_fma(a, b, c);
}

// ---------------------------------------------------------------------------
// Fully-fused attention: BLOCK-LOCAL split-K, no workspace, no 2nd kernel.
// (R10 configuration — session best: 71.8 us kernel / 115.8 us total.)
//   - block = 256 threads = 4 waves; block owns 128 q-rows (QPT=2 per lane).
//   - wave w processes k-quarter w (512 of 2048 k-rows).
//   - k staged in 2 chunks of 1024 rows (32 KB LDS), head-interleaved
//     (k0,k4,k1,k5)(k2,k6,k3,k7) so both heads ride lo/hi halves of v_pk_*.
//     Wave LDS reads are single-address broadcasts (conflict-free).
//   - chunk 1 global loads prefetched into registers across chunk 0 compute.
//   - scores bounded [-2,2] (h = cos(..)) -> single-pass exp, no max needed.
//   - merge: waves 1-3 dump 20 partial floats via LDS (stride 21, gcd(21,32)
//     =1 -> conflict-free), wave 0 sums, normalizes, projects W_out, stores.
// Session ledger (why this shape): packed-f32 2-head math -23%; block-local
// split-K -16us total; occupancy/LDS-traffic/exp-pipelining/barriers all
// neutral (wall = 1.35 x VALU-issue, invariant); poly-exp and f16-fdot2
// both regressed (trans pipe is NOT the limiter; fdot2 is pk-rate).
// ---------------------------------------------------------------------------
__global__ __launch_bounds__(256, 2) void attn_fused_kernel(
    const float* __restrict__ x, const float* __restrict__ theta,
    const float* __restrict__ Wout, float* __restrict__ outp) {
  // 1024 rows x 8 floats = 32 KB; reused as the merge buffer at the end.
  __shared__ __align__(16) float kv[1024 * 8];

  const int b = blockIdx.y;
  const int t = threadIdx.x;
  const int w = t >> 6;    // wave index == k-quarter
  const int lane = t & 63;
  const int qbase = blockIdx.x * 128;

  float th[8];
#pragma unroll
  for (int e = 0; e < 8; ++e) th[e] = theta[e];

  // ---- stage chunk 0 (1024 rows; 256 per quarter) ----
#pragma unroll
  for (int i = 0; i < 4; ++i) {
    const int l = t + 256 * i;
    const int qtr = l >> 8;
    const int rr = l & 255;
    const int gk = qtr * 512 + rr;  // chunk 0
    const float4* xr = (const float4*)(x + ((size_t)b * NS + gk) * 8);
    float4 lo = xr[0], hi = xr[1];
    lo.x = __cosf(lo.x + th[0]);
    lo.y = __cosf(lo.y + th[1]);
    lo.z = __cosf(lo.z + th[2]);
    lo.w = __cosf(lo.w + th[3]);
    hi.x = __cosf(hi.x + th[4]);
    hi.y = __cosf(hi.y + th[5]);
    hi.z = __cosf(hi.z + th[6]);
    hi.w = __cosf(hi.w + th[7]);
    ((float4*)kv)[2 * l] = make_float4(lo.x, hi.x, lo.y, hi.y);
    ((float4*)kv)[2 * l + 1] = make_float4(lo.z, hi.z, lo.w, hi.w);
  }

  // ---- prefetch chunk 1's raw x rows into registers ----
  float4 pf[4][2];
#pragma unroll
  for (int i = 0; i < 4; ++i) {
    const int l = t + 256 * i;
    const int qtr = l >> 8;
    const int rr = l & 255;
    const int gk = qtr * 512 + 256 + rr;  // chunk 1
    const float4* xr = (const float4*)(x + ((size_t)b * NS + gk) * 8);
    pf[i][0] = xr[0];
    pf[i][1] = xr[1];
  }

  // This lane's 2 query rows as head-interleaved pairs, pre-scaled.
  v2f qp[2][4];
#pragma unroll
  for (int g = 0; g < 2; ++g) {
    const float4* xq =
        (const float4*)(x + ((size_t)b * NS + qbase + 64 * g + lane) * 8);
    float4 lo = xq[0], hi = xq[1];
    qp[g][0] = (v2f){__cosf(lo.x + th[0]) * QSCALE, __cosf(hi.x + th[4]) * QSCALE};
    qp[g][1] = (v2f){__cosf(lo.y + th[1]) * QSCALE, __cosf(hi.y + th[5]) * QSCALE};
    qp[g][2] = (v2f){__cosf(lo.z + th[2]) * QSCALE, __cosf(hi.z + th[6]) * QSCALE};
    qp[g][3] = (v2f){__cosf(lo.w + th[3]) * QSCALE, __cosf(hi.w + th[7]) * QSCALE};
  }

  v2f acc[2][4];  // acc[g][i] = (sum p0*k_i, sum p1*k_{4+i})
  v2f den[2];     // (sum p0, sum p1)
#pragma unroll
  for (int g = 0; g < 2; ++g) {
    acc[g][0] = (v2f){0.f, 0.f};
    acc[g][1] = (v2f){0.f, 0.f};
    acc[g][2] = (v2f){0.f, 0.f};
    acc[g][3] = (v2f){0.f, 0.f};
    den[g] = (v2f){0.f, 0.f};
  }

  __syncthreads();  // (1) chunk 0 staged

  // ---- compute chunk 0: wave w reads LDS rows [w*256, w*256+256) ----
  {
    const v4f* kp = (const v4f*)kv + (size_t)w * 512;
#pragma unroll 4
    for (int j = 0; j < 256; ++j) {
      v4f A = kp[2 * j];
      v4f Bv = kp[2 * j + 1];
      v2f kk0 = A.xy, kk1 = A.zw, kk2 = Bv.xy, kk3 = Bv.zw;
#pragma unroll
      for (int g = 0; g < 2; ++g) {
        v2f s = qp[g][0] * kk0;
        s = pkfma(qp[g][1], kk1, s);
        s = pkfma(qp[g][2], kk2, s);
        s = pkfma(qp[g][3], kk3, s);
        v2f P;
        P.x = __builtin_amdgcn_exp2f(s.x);
        P.y = __builtin_amdgcn_exp2f(s.y);
        acc[g][0] = pkfma(P, kk0, acc[g][0]);
        acc[g][1] = pkfma(P, kk1, acc[g][1]);
        acc[g][2] = pkfma(P, kk2, acc[g][2]);
        acc[g][3] = pkfma(P, kk3, acc[g][3]);
        den[g] = den[g] + P;
      }
    }
  }

  __syncthreads();  // (2) chunk 0 fully consumed

  // ---- restage chunk 1 from prefetched registers (no memory latency) ----
#pragma unroll
  for (int i = 0; i < 4; ++i) {
    const int l = t + 256 * i;
    float4 lo = pf[i][0], hi = pf[i][1];
    lo.x = __cosf(lo.x + th[0]);
    lo.y = __cosf(lo.y + th[1]);
    lo.z = __cosf(lo.z + th[2]);
    lo.w = __cosf(lo.w + th[3]);
    hi.x = __cosf(hi.x + th[4]);
    hi.y = __cosf(hi.y + th[5]);
    hi.z = __cosf(hi.z + th[6]);
    hi.w = __cosf(hi.w + th[7]);
    ((float4*)kv)[2 * l] = make_float4(lo.x, hi.x, lo.y, hi.y);
    ((float4*)kv)[2 * l + 1] = make_float4(lo.z, hi.z, lo.w, hi.w);
  }

  __syncthreads();  // (3) chunk 1 staged

  // ---- compute chunk 1 ----
  {
    const v4f* kp = (const v4f*)kv + (size_t)w * 512;
#pragma unroll 4
    for (int j = 0; j < 256; ++j) {
      v4f A = kp[2 * j];
      v4f Bv = kp[2 * j + 1];
      v2f kk0 = A.xy, kk1 = A.zw, kk2 = Bv.xy, kk3 = Bv.zw;
#pragma unroll
      for (int g = 0; g < 2; ++g) {
        v2f s = qp[g][0] * kk0;
        s = pkfma(qp[g][1], kk1, s);
        s = pkfma(qp[g][2], kk2, s);
        s = pkfma(qp[g][3], kk3, s);
        v2f P;
        P.x = __builtin_amdgcn_exp2f(s.x);
        P.y = __builtin_amdgcn_exp2f(s.y);
        acc[g][0] = pkfma(P, kk0, acc[g][0]);
        acc[g][1] = pkfma(P, kk1, acc[g][1]);
        acc[g][2] = pkfma(P, kk2, acc[g][2]);
        acc[g][3] = pkfma(P, kk3, acc[g][3]);
        den[g] = den[g] + P;
      }
    }
  }

  // ---- block-local split-K merge through LDS ----
  __syncthreads();  // (4) all waves done reading kv as k-tiles
  if (w > 0) {
    // stride 21 floats per lane: gcd(21,32)=1 -> no systematic bank conflict
    float* mb = kv + ((size_t)(w - 1) * 64 + lane) * 21;
#pragma unroll
    for (int g = 0; g < 2; ++g) {
      mb[10 * g + 0] = acc[g][0].x;
      mb[10 * g + 1] = acc[g][0].y;
      mb[10 * g + 2] = acc[g][1].x;
      mb[10 * g + 3] = acc[g][1].y;
      mb[10 * g + 4] = acc[g][2].x;
      mb[10 * g + 5] = acc[g][2].y;
      mb[10 * g + 6] = acc[g][3].x;
      mb[10 * g + 7] = acc[g][3].y;
      mb[10 * g + 8] = den[g].x;
      mb[10 * g + 9] = den[g].y;
    }
  }
  __syncthreads();  // (5)
  if (w == 0) {
#pragma unroll
    for (int m = 0; m < 3; ++m) {
      const float* mb = kv + ((size_t)m * 64 + lane) * 21;
#pragma unroll
      for (int g = 0; g < 2; ++g) {
        acc[g][0].x += mb[10 * g + 0];
        acc[g][0].y += mb[10 * g + 1];
        acc[g][1].x += mb[10 * g + 2];
        acc[g][1].y += mb[10 * g + 3];
        acc[g][2].x += mb[10 * g + 4];
        acc[g][2].y += mb[10 * g + 5];
        acc[g][3].x += mb[10 * g + 6];
        acc[g][3].y += mb[10 * g + 7];
        den[g].x += mb[10 * g + 8];
        den[g].y += mb[10 * g + 9];
      }
    }
    // normalize + project (out = m @ W_out^T) + store
#pragma unroll
    for (int g = 0; g < 2; ++g) {
      const int q = qbase + 64 * g + lane;
      const float i0 = 1.0f / den[g].x, i1 = 1.0f / den[g].y;
      float m8[8] = {acc[g][0].x * i0, acc[g][1].x * i0, acc[g][2].x * i0,
                     acc[g][3].x * i0, acc[g][0].y * i1, acc[g][1].y * i1,
                     acc[g][2].y * i1, acc[g][3].y * i1};
      float o[8];
#pragma unroll
      for (int e = 0; e < 8; ++e) {
        float s = 0.f;
#pragma unroll
        for (int f = 0; f < 8; ++f) s += m8[f] * Wout[e * 8 + f];
        o[e] = s;
      }
      float4* op = (float4*)(outp + ((size_t)b * NS + q) * 8);
      op[0] = make_float4(o[0], o[1], o[2], o[3]);
      op[1] = make_float4(o[4], o[5], o[6], o[7]);
    }
  }
}

extern "C" void kernel_launch(void* const* d_in, const int* in_sizes, int n_in,
                              void* d_out, int out_size, void* d_ws,
                              size_t ws_size, hipStream_t stream) {
  const float* x = (const float*)d_in[0];      // [32, 2048, 8]
  const float* theta = (const float*)d_in[1];  // [8]
  const float* W = (const float*)d_in[2];      // [8, 8]
  float* out = (float*)d_out;                  // [32, 2048, 8]
  (void)d_ws;
  (void)ws_size;

  // 512 blocks (16 q-chunks x 32 batches) = 2 blocks/CU (32 KB LDS each),
  // 8 waves/CU.
  attn_fused_kernel<<<dim3(NS / 128, NB), 256, 0, stream>>>(x, theta, W, out);
}